// Round 1
// 260.550 us; speedup vs baseline: 1.0365x; 1.0365x over previous
//
#include <hip/hip_runtime.h>
#include <hip/hip_bf16.h>
#include <stdint.h>

typedef __bf16 bf16_t;
typedef __bf16 bf16x8 __attribute__((ext_vector_type(8)));
typedef float f32x4 __attribute__((ext_vector_type(4)));

#define NB      4
#define T_TXT   2048
#define T_IMG   8
#define N_LAT   64
#define DIM     2048
#define DIM_VIS 1024
#define HEADS   8
#define DHEAD   64
#define INNER   512

__device__ __forceinline__ void gld_lds16(const void* g, void* l) {
    __builtin_amdgcn_global_load_lds((const __attribute__((address_space(1))) void*)g,
                                     (__attribute__((address_space(3))) void*)l,
                                     16, 0, 0);
}

// ---------- fused transpose + fp32->bf16 convert for the 3 weight matrices ----
// grid = (1024, 3); each matrix has exactly (R/32)*(C/32) = 1024 tiles.
__global__ __launch_bounds__(256) void transpose3_k(const float* __restrict__ Wq,
                                                    const float* __restrict__ Wkv,
                                                    const float* __restrict__ Wout,
                                                    bf16_t* __restrict__ WqT,
                                                    bf16_t* __restrict__ WkvT,
                                                    bf16_t* __restrict__ WoutT) {
    __shared__ float tile[32][33];
    const float* in; bf16_t* out; int R, C;
    int which = blockIdx.y;
    if (which == 0)      { in = Wq;   out = WqT;   R = 2048; C = 512;  }
    else if (which == 1) { in = Wkv;  out = WkvT;  R = 1024; C = 1024; }
    else                 { in = Wout; out = WoutT; R = 512;  C = 2048; }
    int nbx = C >> 5;
    int bx = blockIdx.x % nbx, by = blockIdx.x / nbx;
    int c0 = bx * 32, r0 = by * 32;
    int x = threadIdx.x, y = threadIdx.y;  // 32 x 8
#pragma unroll
    for (int d = 0; d < 4; d++)
        tile[y + d * 8][x] = in[(size_t)(r0 + y + d * 8) * C + c0 + x];
    __syncthreads();
#pragma unroll
    for (int d = 0; d < 4; d++)
        out[(size_t)(c0 + y + d * 8) * R + r0 + x] = (bf16_t)tile[x][y + d * 8];
}

// ---------- elementwise fp32 -> bf16 ------------------------------------------
__global__ __launch_bounds__(256) void cvt_k(const float* __restrict__ in,
                                             bf16_t* __restrict__ out) {
    int idx = (blockIdx.x * 256 + threadIdx.x) * 8;
    f32x4 a = *(const f32x4*)(in + idx);
    f32x4 b = *(const f32x4*)(in + idx + 4);
    bf16x8 o;
#pragma unroll
    for (int i = 0; i < 4; i++) { o[i] = (bf16_t)a[i]; o[i + 4] = (bf16_t)b[i]; }
    *(bf16x8*)(out + idx) = o;
}

// ---------- LayerNorm: fp32 in, bf16 out; one block per row of 2048 -----------
__global__ __launch_bounds__(256) void ln_k(const float* __restrict__ x,
                                            const float* __restrict__ gamma,
                                            const float* __restrict__ beta,
                                            bf16_t* __restrict__ xn) {
    int row = blockIdx.x;
    int t = threadIdx.x;
    const float* xp = x + (size_t)row * DIM + t * 8;
    f32x4 v0 = *(const f32x4*)xp;
    f32x4 v1 = *(const f32x4*)(xp + 4);
    float f[8];
    float s = 0.f, ss = 0.f;
#pragma unroll
    for (int i = 0; i < 4; i++) { f[i] = v0[i]; f[i + 4] = v1[i]; }
#pragma unroll
    for (int i = 0; i < 8; i++) { s += f[i]; ss += f[i] * f[i]; }
#pragma unroll
    for (int off = 32; off > 0; off >>= 1) { s += __shfl_xor(s, off); ss += __shfl_xor(ss, off); }
    __shared__ float sbuf[4], sbuf2[4];
    int wid = t >> 6, lane = t & 63;
    if (lane == 0) { sbuf[wid] = s; sbuf2[wid] = ss; }
    __syncthreads();
    s  = sbuf[0] + sbuf[1] + sbuf[2] + sbuf[3];
    ss = sbuf2[0] + sbuf2[1] + sbuf2[2] + sbuf2[3];
    float mu  = s * (1.0f / DIM);
    float var = ss * (1.0f / DIM) - mu * mu;
    float rs  = rsqrtf(var + 1e-5f);
    f32x4 g0 = *(const f32x4*)(gamma + t * 8);
    f32x4 g1 = *(const f32x4*)(gamma + t * 8 + 4);
    f32x4 b0 = *(const f32x4*)(beta + t * 8);
    f32x4 b1 = *(const f32x4*)(beta + t * 8 + 4);
    bf16x8 o;
#pragma unroll
    for (int i = 0; i < 4; i++) {
        o[i]     = (bf16_t)((f[i]     - mu) * rs * g0[i] + b0[i]);
        o[i + 4] = (bf16_t)((f[i + 4] - mu) * rs * g1[i] + b1[i]);
    }
    *(bf16x8*)(xn + (size_t)row * DIM + t * 8) = o;
}

// ---------- GEMM: C[MxN] = A[MxK] * Bt[NxK]^T, bf16 in, fp32 accum, OT out ---
// 128x128 tile, BK=32, double-buffered 2-phase pipeline (stage t+1 before
// computing t; single barrier per K-step — its implicit vmcnt(0) drain is the
// pipeline wait). 1D grid with in-kernel bijective XCD swizzle: each XCD gets
// a contiguous y-major chunk so the N-block quad sharing an A panel co-resides
// on one XCD's L2. Split-K via bz: slice covers K range [bz*Kper, (bz+1)*Kper)
// and writes to C + bz*M*N. TAG distinguishes dispatches.
template <int TAG, typename OT>
__global__ __launch_bounds__(256) void gemm_bt(const bf16_t* __restrict__ A,
                                               const bf16_t* __restrict__ Bt,
                                               OT* __restrict__ C,
                                               int M, int N, int K, int Kper,
                                               float scale,
                                               int gx, int gy, int gz) {
    __shared__ __align__(16) bf16_t lA[2][128 * 32];
    __shared__ __align__(16) bf16_t lB[2][128 * 32];
    int tid = threadIdx.x;
    int w = tid >> 6, lane = tid & 63;
    int wm = w >> 1, wn = w & 1;

    // bijective XCD swizzle (nwg % 8 == 0 for all 3 dispatches)
    int nwg = gx * gy * gz;
    int cpx = nwg >> 3;
    int nid = (blockIdx.x & 7) * cpx + (blockIdx.x >> 3);
    int tpy = gx * gz;
    int by = nid / tpy;
    int rr = nid - by * tpy;
    int bz = rr / gx;
    int bx = rr - bz * gx;

    int bm0 = by * 128, bn0 = bx * 128;
    int kbase = bz * Kper;
    int q = lane >> 4, l16 = lane & 15;

    int c0 = w * 64 + lane;
    int r0 = c0 >> 2, cc0 = c0 & 3;
    int c1 = 256 + c0;
    int r1 = c1 >> 2, cc1 = c1 & 3;
    const bf16_t* pA0 = A + (size_t)(bm0 + r0) * K + kbase + cc0 * 8;
    const bf16_t* pA1 = A + (size_t)(bm0 + r1) * K + kbase + cc1 * 8;
    const bf16_t* pB0 = Bt + (size_t)(bn0 + r0) * K + kbase + cc0 * 8;
    const bf16_t* pB1 = Bt + (size_t)(bn0 + r1) * K + kbase + cc1 * 8;

    f32x4 acc[4][4];
#pragma unroll
    for (int i = 0; i < 4; i++)
#pragma unroll
        for (int j = 0; j < 4; j++)
            acc[i][j] = (f32x4){0.f, 0.f, 0.f, 0.f};

    auto stage = [&](int buf, int k0) {
        gld_lds16(pA0 + k0, &lA[buf][w * 512]);
        gld_lds16(pA1 + k0, &lA[buf][2048 + w * 512]);
        gld_lds16(pB0 + k0, &lB[buf][w * 512]);
        gld_lds16(pB1 + k0, &lB[buf][2048 + w * 512]);
    };
    auto compute = [&](int buf) {
        bf16x8 af[4], bfr[4];
#pragma unroll
        for (int mt = 0; mt < 4; mt++)
            af[mt] = *(const bf16x8*)(&lA[buf][(wm * 64 + mt * 16 + l16) * 32 + q * 8]);
#pragma unroll
        for (int nt = 0; nt < 4; nt++)
            bfr[nt] = *(const bf16x8*)(&lB[buf][(wn * 64 + nt * 16 + l16) * 32 + q * 8]);
#pragma unroll
        for (int mt = 0; mt < 4; mt++)
#pragma unroll
            for (int nt = 0; nt < 4; nt++)
                acc[mt][nt] = __builtin_amdgcn_mfma_f32_16x16x32_bf16(af[mt], bfr[nt], acc[mt][nt], 0, 0, 0);
    };

    // prologue
    stage(0, 0);
    __syncthreads();
    int cur = 0;
    for (int k0 = 32; k0 < Kper; k0 += 32) {
        stage(cur ^ 1, k0);     // issue next tile's loads first
        compute(cur);           // hide their latency under ds_read + MFMA
        __syncthreads();        // implicit vmcnt(0)+lgkmcnt(0) drain
        cur ^= 1;
    }
    compute(cur);               // epilogue tile (already staged + drained)

    OT* Cz = C + (size_t)bz * M * N;
#pragma unroll
    for (int mt = 0; mt < 4; mt++)
#pragma unroll
        for (int nt = 0; nt < 4; nt++)
#pragma unroll
            for (int r = 0; r < 4; r++) {
                int row = bm0 + wm * 64 + mt * 16 + q * 4 + r;
                int col = bn0 + wn * 64 + nt * 16 + l16;
                Cz[(size_t)row * N + col] = (OT)(acc[mt][nt][r] * scale);
            }
}

// ---------- reduce 4 bf16 split-K slices -> bf16, with scale ------------------
__global__ __launch_bounds__(256) void reduce4_k(const bf16_t* __restrict__ p,
                                                 bf16_t* __restrict__ o,
                                                 size_t n, float scale) {
    size_t i = ((size_t)blockIdx.x * 256 + threadIdx.x) * 8;
    bf16x8 a0 = *(const bf16x8*)(p + i);
    bf16x8 a1 = *(const bf16x8*)(p + n + i);
    bf16x8 a2 = *(const bf16x8*)(p + 2 * n + i);
    bf16x8 a3 = *(const bf16x8*)(p + 3 * n + i);
    bf16x8 r;
#pragma unroll
    for (int u = 0; u < 8; u++)
        r[u] = (bf16_t)(((float)a0[u] + (float)a1[u] + (float)a2[u] + (float)a3[u]) * scale);
    *(bf16x8*)(o + i) = r;
}

// ---------- cumsum + contiguous bucket ranges (NO atomics) --------------------
// Queries attending image t form the contiguous token range
// [pos of t-th media token, pos of (t+1)-th). The media token whose inclusive
// cumsum equals c is the unique writer of bstart[b*8+c-1]; counts come from
// differencing with a T_TXT sentinel (duplicate positions -> empty tail buckets).
// Storage mode auto-detected: uint8 / int32 / fp32 (reads first 8KB only).
__global__ __launch_bounds__(256) void cumsum_bucket_k(const void* __restrict__ locs,
                                                       int* __restrict__ bstart,
                                                       int* __restrict__ bcnt) {
    int b = blockIdx.x, t = threadIdx.x;
    const unsigned* up = (const unsigned*)locs;
    const int* ip = (const int*)locs;
    const unsigned char* bp = (const unsigned char*)locs;
    const float* fp = (const float*)locs;

    int other = 0, nf = 0;
#pragma unroll
    for (int i = 0; i < 8; i++) {
        unsigned wv = up[t * 8 + i];
        nf    += (wv == 0x3F800000u);
        other += (wv != 0u && wv != 1u && wv != 0x3F800000u);
    }
#pragma unroll
    for (int off = 32; off > 0; off >>= 1) { other += __shfl_xor(other, off); nf += __shfl_xor(nf, off); }
    __shared__ int so[4], sf[4];
    int wid = t >> 6, lane = t & 63;
    if (lane == 0) { so[wid] = other; sf[wid] = nf; }
    __syncthreads();
    other = so[0] + so[1] + so[2] + so[3];
    nf    = sf[0] + sf[1] + sf[2] + sf[3];
    int mode = (other > 0) ? 0 : ((nf > 0) ? 2 : 1);   // 0=u8, 1=i32, 2=f32

    int v[8];
    int s = 0;
#pragma unroll
    for (int i = 0; i < 8; i++) {
        int idx = b * T_TXT + t * 8 + i;
        int xv;
        if (mode == 1)      xv = ip[idx];
        else if (mode == 0) xv = (int)bp[idx];
        else                xv = (fp[idx] != 0.f) ? 1 : 0;
        v[i] = xv;
        s += xv;
    }
    __shared__ int sc[256];
    __shared__ int sstart[T_IMG];
    if (t < T_IMG) sstart[t] = T_TXT;   // sentinel
    sc[t] = s;
    __syncthreads();
    for (int off = 1; off < 256; off <<= 1) {
        int add = (t >= off) ? sc[t - off] : 0;
        __syncthreads();
        sc[t] += add;
        __syncthreads();
    }
    int run = sc[t] - s;   // exclusive prefix of this thread's chunk
#pragma unroll
    for (int i = 0; i < 8; i++) {
        run += v[i];
        if (v[i] && run <= T_IMG) sstart[run - 1] = t * 8 + i;  // unique writer
    }
    __syncthreads();
    if (t < T_IMG) {
        int st = sstart[t];
        int nx = (t + 1 < T_IMG) ? sstart[t + 1] : T_TXT;
        bstart[b * T_IMG + t] = st;
        bcnt[b * T_IMG + t]   = nx - st;   // 0 for empty tail buckets
    }
}

// ---------- MFMA bucketed attention (contiguous query ranges) -----------------
// Block = (bucket = b*8 + timg, head). Stages K_h [64x64] row-major and
// V_h transposed [d][key] into LDS; each wave handles 16-query chunks:
// QK^T (8 MFMA) -> quad-shuffle softmax -> P via wave-private LDS (C->A layout)
// -> PV (8 MFMA) -> store. q is pre-scaled by 0.125.
__global__ __launch_bounds__(256) void attn_mfma_k(const bf16_t* __restrict__ q,
                                                   const bf16_t* __restrict__ kv,
                                                   const int* __restrict__ bstart,
                                                   const int* __restrict__ bcnt,
                                                   bf16_t* __restrict__ aout) {
    __shared__ __align__(16) bf16_t lK[64 * 64];
    __shared__ __align__(16) bf16_t lVt[64 * 64];
    __shared__ __align__(16) bf16_t lP[4][16 * 64];

    int bucket = blockIdx.x >> 3;
    int h = blockIdx.x & 7;
    int n_q = bcnt[bucket];
    if (n_q <= 0) return;
    int b = bucket >> 3;
    int timg = bucket & 7;
    int row0 = b * T_TXT + bstart[bucket];   // first query row (global)
    size_t krow0 = (size_t)(b * (T_IMG * N_LAT) + timg * N_LAT);

    int tid = threadIdx.x;
    int wid = tid >> 6, lane = tid & 63;
    int quad = lane >> 4, l16 = lane & 15;

    {
        const bf16_t* s0 = kv + (krow0 + 16 * wid + (lane >> 3)) * (2 * INNER) + h * DHEAD + (lane & 7) * 8;
        const bf16_t* s1 = kv + (krow0 + 16 * wid + 8 + (lane >> 3)) * (2 * INNER) + h * DHEAD + (lane & 7) * 8;
        gld_lds16(s0, lK + wid * 1024);
        gld_lds16(s1, lK + wid * 1024 + 512);
    }
    {
        int key = tid & 63, dblk = tid >> 6;
        const bf16_t* vsrc = kv + (krow0 + key) * (2 * INNER) + INNER + h * DHEAD + dblk * 16;
        bf16x8 v0 = *(const bf16x8*)vsrc;
        bf16x8 v1 = *(const bf16x8*)(vsrc + 8);
#pragma unroll
        for (int u = 0; u < 8; u++) {
            lVt[(dblk * 16 + u) * 64 + key]     = v0[u];
            lVt[(dblk * 16 + 8 + u) * 64 + key] = v1[u];
        }
    }
    __syncthreads();

    for (int c0 = wid * 16; c0 < n_q; c0 += 64) {
        int qi = row0 + c0 + ((c0 + l16 < n_q) ? l16 : 0);   // contiguous rows

        const bf16_t* qrow = q + (size_t)qi * INNER + h * DHEAD + quad * 8;
        bf16x8 qf0 = *(const bf16x8*)qrow;
        bf16x8 qf1 = *(const bf16x8*)(qrow + 32);
        f32x4 s[4];
#pragma unroll
        for (int nt = 0; nt < 4; nt++) s[nt] = (f32x4){0.f, 0.f, 0.f, 0.f};
#pragma unroll
        for (int nt = 0; nt < 4; nt++) {
            bf16x8 kf0 = *(const bf16x8*)(lK + (l16 + 16 * nt) * 64 + quad * 8);
            bf16x8 kf1 = *(const bf16x8*)(lK + (l16 + 16 * nt) * 64 + 32 + quad * 8);
            s[nt] = __builtin_amdgcn_mfma_f32_16x16x32_bf16(qf0, kf0, s[nt], 0, 0, 0);
            s[nt] = __builtin_amdgcn_mfma_f32_16x16x32_bf16(qf1, kf1, s[nt], 0, 0, 0);
        }

        float mr[4];
#pragma unroll
        for (int r = 0; r < 4; r++) {
            float m = fmaxf(fmaxf(s[0][r], s[1][r]), fmaxf(s[2][r], s[3][r]));
#pragma unroll
            for (int off = 8; off >= 1; off >>= 1) m = fmaxf(m, __shfl_xor(m, off));
            mr[r] = m;
        }
        float p[4][4];
#pragma unroll
        for (int nt = 0; nt < 4; nt++)
#pragma unroll
            for (int r = 0; r < 4; r++)
                p[nt][r] = __expf(s[nt][r] - mr[r]);
#pragma unroll
        for (int r = 0; r < 4; r++) {
            float tsum = p[0][r] + p[1][r] + p[2][r] + p[3][r];
#pragma unroll
            for (int off = 8; off >= 1; off >>= 1) tsum += __shfl_xor(tsum, off);
            float inv = 1.0f / tsum;
            p[0][r] *= inv; p[1][r] *= inv; p[2][r] *= inv; p[3][r] *= inv;
        }

        bf16_t* pt = lP[wid];
#pragma unroll
        for (int nt = 0; nt < 4; nt++)
#pragma unroll
            for (int r = 0; r < 4; r++)
                pt[(quad * 4 + r) * 64 + 16 * nt + l16] = (bf16_t)p[nt][r];
        asm volatile("s_waitcnt lgkmcnt(0)" ::: "memory");

        bf16x8 pf0 = *(const bf16x8*)(pt + l16 * 64 + quad * 8);
        bf16x8 pf1 = *(const bf16x8*)(pt + l16 * 64 + 32 + quad * 8);
        f32x4 o[4];
#pragma unroll
        for (int ntd = 0; ntd < 4; ntd++) o[ntd] = (f32x4){0.f, 0.f, 0.f, 0.f};
#pragma unroll
        for (int ntd = 0; ntd < 4; ntd++) {
            bf16x8 vf0 = *(const bf16x8*)(lVt + (l16 + 16 * ntd) * 64 + quad * 8);
            bf16x8 vf1 = *(const bf16x8*)(lVt + (l16 + 16 * ntd) * 64 + 32 + quad * 8);
            o[ntd] = __builtin_amdgcn_mfma_f32_16x16x32_bf16(pf0, vf0, o[ntd], 0, 0, 0);
            o[ntd] = __builtin_amdgcn_mfma_f32_16x16x32_bf16(pf1, vf1, o[ntd], 0, 0, 0);
        }

        // store: query = c0 + quad*4 + r (contiguous), col = l16 + 16*ntd
#pragma unroll
        for (int r = 0; r < 4; r++) {
            int qidx = c0 + quad * 4 + r;
            if (qidx < n_q) {
                bf16_t* op = aout + (size_t)(row0 + qidx) * INNER + h * DHEAD + l16;
#pragma unroll
                for (int ntd = 0; ntd < 4; ntd++)
                    op[16 * ntd] = (bf16_t)o[ntd][r];
            }
        }
    }
}

// ---------- launch ------------------------------------------------------------
extern "C" void kernel_launch(void* const* d_in, const int* in_sizes, int n_in,
                              void* d_out, int out_size, void* d_ws, size_t ws_size,
                              hipStream_t stream) {
    const float* x     = (const float*)d_in[0];
    const float* media = (const float*)d_in[1];
    const void*  locs  = d_in[2];
    const float* gamma = (const float*)d_in[3];
    const float* beta  = (const float*)d_in[4];
    const float* Wq    = (const float*)d_in[5];
    const float* Wkv   = (const float*)d_in[6];
    const float* Wout  = (const float*)d_in[7];
    float* out = (float*)d_out;

    // d_out (64MB fp32) doubles as scratch before GEMM3 overwrites it:
    //   lower 32MB: xn (bf16 LN output, GEMM1's A)
    //   upper 32MB: split-K bf16 partials (GEMM1: 16MB, then GEMM2: 16MB)
    bf16_t* xn   = (bf16_t*)d_out;
    bf16_t* part = (bf16_t*)d_out + (size_t)16 * 1024 * 1024;

    char* p = (char*)d_ws;
    bf16_t* qbuf   = (bf16_t*)p; p += (size_t)8192 * 512 * 2;    // 8 MB
    bf16_t* aout   = (bf16_t*)p; p += (size_t)8192 * 512 * 2;    // 8 MB
    bf16_t* kvbuf  = (bf16_t*)p; p += (size_t)2048 * 1024 * 2;   // 4 MB
    bf16_t* mediab = (bf16_t*)p; p += (size_t)2048 * 1024 * 2;   // 4 MB
    bf16_t* WqT    = (bf16_t*)p; p += (size_t)512 * 2048 * 2;    // 2 MB
    bf16_t* WkvT   = (bf16_t*)p; p += (size_t)1024 * 1024 * 2;   // 2 MB
    bf16_t* WoutT  = (bf16_t*)p; p += (size_t)2048 * 512 * 2;    // 2 MB
    int*    bstart = (int*)p;    p += 32 * sizeof(int);
    int*    bcnt   = (int*)p;    p += 32 * sizeof(int);

    transpose3_k<<<dim3(1024, 3), dim3(32, 8), 0, stream>>>(Wq, Wkv, Wout, WqT, WkvT, WoutT);
    cvt_k<<<(2048 * 1024) / (256 * 8), 256, 0, stream>>>(media, mediab);

    ln_k<<<8192, 256, 0, stream>>>(x, gamma, beta, xn);

    // GEMM1: q_partials = xn @ Wq, split-K=4 (Kper=512), 1024 blocks
    gemm_bt<1, bf16_t><<<1024, 256, 0, stream>>>(xn, WqT, part, 8192, 512, 2048, 512, 1.0f, 4, 64, 4);
    reduce4_k<<<2048, 256, 0, stream>>>(part, qbuf, (size_t)8192 * 512, 0.125f);

    // GEMM2: kv_partials = media @ Wkv, split-K=4 (Kper=256), 512 blocks
    gemm_bt<2, bf16_t><<<512, 256, 0, stream>>>(mediab, WkvT, part, 2048, 1024, 1024, 256, 1.0f, 8, 16, 4);
    reduce4_k<<<1024, 256, 0, stream>>>(part, kvbuf, (size_t)2048 * 1024, 1.0f);

    cumsum_bucket_k<<<NB, 256, 0, stream>>>(locs, bstart, bcnt);

    hipMemsetAsync(aout, 0, (size_t)8192 * 512 * 2, stream);

    attn_mfma_k<<<32 * HEADS, 256, 0, stream>>>(qbuf, kvbuf, bstart, bcnt, aout);

    // GEMM3: out = aout @ Wout (fp32 out, no split: 1024 blocks already)
    gemm_bt<3, float><<<1024, 256, 0, stream>>>(aout, WoutT, out, 8192, 2048, 512, 512, 1.0f, 16, 64, 1);
}